// Round 4
// baseline (1138.811 us; speedup 1.0000x reference)
//
#include <hip/hip_runtime.h>
#include <hip/hip_bf16.h>

// 3-layer GraphConv (PyG) + softmax, 100k nodes, 1.6M edges, all f32.
// R2: f32 global atomics capped at ~306G/s -> pull-gather.
// R3: fine (per-node) CSR bucket scatter caused 16x write amplification
//     (105 MB writeback for 6.4 MB of data, 128 us).
// R4: coarse buckets (R=128 nodes) + LDS accumulation per bucket.
//     Build appends packed 4B records (dst_local<<17 | src) to ~782 regions
//     (dense line fills), per-layer aggregate streams records and ds_add's
//     into a 16/8/1 KB LDS tile. Softmax fused into layer 3.

#define RNODES 128          // nodes per bucket (dst_local fits in 7 bits)
#define NB_MAX 1024         // scan/hist capacity

// ---------------- transform: t = act(x)@Wrel ; acc = act(x)@Wroot + b -------
template <int Fin, int Fout, bool RELU>
__global__ void transform_kernel(const float* __restrict__ x,
                                 const float* __restrict__ Wrel,
                                 const float* __restrict__ Wroot,
                                 const float* __restrict__ bias,
                                 float* __restrict__ t,
                                 float* __restrict__ acc,
                                 int N) {
    __shared__ float sRel[Fin * Fout];
    __shared__ float sRoot[Fin * Fout];
    __shared__ float sB[Fout];
    for (int i = threadIdx.x; i < Fin * Fout; i += blockDim.x) {
        sRel[i]  = Wrel[i];
        sRoot[i] = Wroot[i];
    }
    if (threadIdx.x < Fout) sB[threadIdx.x] = bias[threadIdx.x];
    __syncthreads();

    int n = blockIdx.x * blockDim.x + threadIdx.x;
    if (n >= N) return;

    float xi[Fin];
#pragma unroll
    for (int k = 0; k < Fin; ++k) {
        float v = x[(long)n * Fin + k];
        if (RELU) v = fmaxf(v, 0.0f);
        xi[k] = v;
    }

    for (int f = 0; f < Fout; ++f) {
        float a = 0.0f, r = 0.0f;
#pragma unroll
        for (int k = 0; k < Fin; ++k) {
            a = fmaf(xi[k], sRel[k * Fout + f], a);
            r = fmaf(xi[k], sRoot[k * Fout + f], r);
        }
        t[(long)n * Fout + f]   = a;
        acc[(long)n * Fout + f] = r + sB[f];
    }
}

// ---------------- coarse-bucket build --------------------------------------
__global__ void hist_coarse_kernel(const int* __restrict__ dst,
                                   int* __restrict__ gcount, int nE, int NB) {
    __shared__ int h[NB_MAX];
    for (int i = threadIdx.x; i < NB; i += blockDim.x) h[i] = 0;
    __syncthreads();
    int stride = gridDim.x * blockDim.x;
    for (int e = blockIdx.x * blockDim.x + threadIdx.x; e < nE; e += stride)
        atomicAdd(&h[dst[e] >> 7], 1);
    __syncthreads();
    for (int i = threadIdx.x; i < NB; i += blockDim.x)
        if (h[i]) atomicAdd(&gcount[i], h[i]);
}

// single block, 1024 threads: exclusive scan over NB<=1024 counts.
__global__ void scan_buckets_kernel(const int* __restrict__ gcount,
                                    int* __restrict__ bptr,
                                    int* __restrict__ cursor, int NB, int nE) {
    __shared__ int s[NB_MAX];
    int t = threadIdx.x;
    int own = (t < NB) ? gcount[t] : 0;
    s[t] = own;
    __syncthreads();
    for (int off = 1; off < NB_MAX; off <<= 1) {
        int v = (t >= off) ? s[t - off] : 0;
        __syncthreads();
        s[t] += v;
        __syncthreads();
    }
    if (t < NB) {
        int ex = s[t] - own;
        bptr[t]   = ex;
        cursor[t] = ex;
    }
    if (t == 0) bptr[NB] = nE;
}

__global__ void bucketize_kernel(const int* __restrict__ src,
                                 const int* __restrict__ dst,
                                 int* __restrict__ cursor,
                                 unsigned int* __restrict__ records, int nE) {
    int e = blockIdx.x * blockDim.x + threadIdx.x;
    if (e < nE) {
        int d = dst[e];
        int b = d >> 7;
        int pos = atomicAdd(&cursor[b], 1);
        records[pos] = (unsigned int)src[e] | ((unsigned int)(d & 127) << 17);
    }
}

// ---------------- per-bucket aggregate: LDS accumulation -------------------
// Block b owns nodes [b*R, b*R+nn). acc_lds init = root term; stream bucket
// records, gather t[src][f] with F lanes/edge, ds_add into LDS, write out.
template <int F, int U, bool SOFTMAX>
__global__ void bucket_agg_kernel(const float* __restrict__ t,
                                  const unsigned int* __restrict__ records,
                                  const int* __restrict__ bptr,
                                  const float* __restrict__ rootacc,
                                  float* __restrict__ out, int N) {
    __shared__ float acc[RNODES * F];
    const int b    = blockIdx.x;
    const int base = b * RNODES;
    const int nn   = min(RNODES, N - base);

    for (int i = threadIdx.x; i < nn * F; i += blockDim.x)
        acc[i] = rootacc[(long)base * F + i];
    __syncthreads();

    const int beg   = bptr[b], end = bptr[b + 1];
    const int lanef = threadIdx.x & (F - 1);
    const int egrp  = threadIdx.x / F;
    const int step  = blockDim.x / F;

    int e = beg + egrp;
    for (; e + (U - 1) * step < end; e += U * step) {
        unsigned int rec[U];
        float v[U];
#pragma unroll
        for (int u = 0; u < U; ++u) rec[u] = records[e + u * step];
#pragma unroll
        for (int u = 0; u < U; ++u) v[u] = t[(rec[u] & 0x1FFFFu) * F + lanef];
#pragma unroll
        for (int u = 0; u < U; ++u)
            atomicAdd(&acc[(rec[u] >> 17) * F + lanef], v[u]);
    }
    for (; e < end; e += step) {
        unsigned int rec = records[e];
        atomicAdd(&acc[(rec >> 17) * F + lanef], t[(rec & 0x1FFFFu) * F + lanef]);
    }
    __syncthreads();

    if (!SOFTMAX) {
        for (int i = threadIdx.x; i < nn * F; i += blockDim.x)
            out[(long)base * F + i] = acc[i];
    } else {
        // F==2: one thread per node
        for (int n = threadIdx.x; n < nn; n += blockDim.x) {
            float a = acc[2 * n], c = acc[2 * n + 1];
            float m = fmaxf(a, c);
            float ea = __expf(a - m), ec = __expf(c - m);
            float inv = 1.0f / (ea + ec);
            out[(long)(base + n) * 2]     = ea * inv;
            out[(long)(base + n) * 2 + 1] = ec * inv;
        }
    }
}

// ---------------- fallback (R2 atomic path) --------------------------------
template <int F>
__global__ void scatter_kernel(const float* __restrict__ t,
                               const int* __restrict__ src,
                               const int* __restrict__ dst,
                               float* __restrict__ acc, int nE) {
    int tid = blockIdx.x * blockDim.x + threadIdx.x;
    int e = tid / F;
    if (e >= nE) return;
    int f = tid & (F - 1);
    atomicAdd(acc + (long)dst[e] * F + f, t[(long)src[e] * F + f]);
}

__global__ void softmax2_kernel(const float* __restrict__ h, float* __restrict__ out, int N) {
    int n = blockIdx.x * blockDim.x + threadIdx.x;
    if (n >= N) return;
    float a = h[2 * n], b = h[2 * n + 1];
    float m = fmaxf(a, b);
    float ea = __expf(a - m), eb = __expf(b - m);
    float inv = 1.0f / (ea + eb);
    out[2 * n] = ea * inv;
    out[2 * n + 1] = eb * inv;
}

extern "C" void kernel_launch(void* const* d_in, const int* in_sizes, int n_in,
                              void* d_out, int out_size, void* d_ws, size_t ws_size,
                              hipStream_t stream) {
    const float* z      = (const float*)d_in[0];
    const int*   ei     = (const int*)d_in[1];
    const float* Wrel1  = (const float*)d_in[2];
    const float* Wroot1 = (const float*)d_in[3];
    const float* b1     = (const float*)d_in[4];
    const float* Wrel2  = (const float*)d_in[5];
    const float* Wroot2 = (const float*)d_in[6];
    const float* b2     = (const float*)d_in[7];
    const float* Wrel3  = (const float*)d_in[8];
    const float* Wroot3 = (const float*)d_in[9];
    const float* b3     = (const float*)d_in[10];

    const int N  = in_sizes[0] / 64;   // 100000
    const int nE = in_sizes[1] / 2;    // 1600000
    const int* src = ei;
    const int* dst = ei + nE;
    const int NB = (N + RNODES - 1) / RNODES;   // 782

    // Float regions (ping-pong, 12.8 MB each):
    //   regionA: t1[N*32] -> { t2[N*16] | h2[N*16] }
    //   regionB: h1[N*32] -> t3[N*2]
    float* regionA = (float*)d_ws;
    float* regionB = regionA + (size_t)N * 32;
    float* t1 = regionA;
    float* h1 = regionB;
    float* t2 = regionA;
    float* h2 = regionA + (size_t)N * 16;
    float* t3 = regionB;
    float* h3 = regionB + (size_t)N * 2;

    // Int region: gcount[NB_MAX], bptr[NB_MAX+1], cursor[NB_MAX], records[nE]
    int* ibase  = (int*)(regionB + (size_t)N * 32);
    int* gcount = ibase;
    int* bptr   = gcount + NB_MAX;
    int* cursor = bptr + NB_MAX + 1;
    unsigned int* records = (unsigned int*)(cursor + NB_MAX);

    size_t needed = (size_t)N * 64 * sizeof(float)
                  + ((size_t)3 * NB_MAX + 1 + (size_t)nE) * sizeof(int);

    const int B = 256;
    const int nodeBlocks = (N + B - 1) / B;
    const int edgeBlocks = (nE + B - 1) / B;
    const bool packOK = (N <= (1 << 17)) && (NB <= NB_MAX);

    if (ws_size >= needed && packOK) {
        // ---- coarse bucket build ----
        hipMemsetAsync(gcount, 0, (size_t)NB * sizeof(int), stream);
        hist_coarse_kernel<<<512, B, 0, stream>>>(dst, gcount, nE, NB);
        scan_buckets_kernel<<<1, NB_MAX, 0, stream>>>(gcount, bptr, cursor, NB, nE);
        bucketize_kernel<<<edgeBlocks, B, 0, stream>>>(src, dst, cursor, records, nE);

        // ---- Layer 1: 64 -> 32 ----
        transform_kernel<64, 32, false><<<nodeBlocks, B, 0, stream>>>(z, Wrel1, Wroot1, b1, t1, h1, N);
        bucket_agg_kernel<32, 8, false><<<NB, B, 0, stream>>>(t1, records, bptr, h1, h1, N);

        // ---- Layer 2: 32 -> 16 ----
        transform_kernel<32, 16, true><<<nodeBlocks, B, 0, stream>>>(h1, Wrel2, Wroot2, b2, t2, h2, N);
        bucket_agg_kernel<16, 8, false><<<NB, B, 0, stream>>>(t2, records, bptr, h2, h2, N);

        // ---- Layer 3: 16 -> 2, softmax fused ----
        transform_kernel<16, 2, true><<<nodeBlocks, B, 0, stream>>>(h2, Wrel3, Wroot3, b3, t3, h3, N);
        bucket_agg_kernel<2, 4, true><<<NB, B, 0, stream>>>(t3, records, bptr, h3, (float*)d_out, N);
    } else {
        // ---- fallback: R2 atomic-scatter path ----
        transform_kernel<64, 32, false><<<nodeBlocks, B, 0, stream>>>(z, Wrel1, Wroot1, b1, t1, h1, N);
        scatter_kernel<32><<<((size_t)nE * 32 + B - 1) / B, B, 0, stream>>>(t1, src, dst, h1, nE);
        transform_kernel<32, 16, true><<<nodeBlocks, B, 0, stream>>>(h1, Wrel2, Wroot2, b2, t2, h2, N);
        scatter_kernel<16><<<((size_t)nE * 16 + B - 1) / B, B, 0, stream>>>(t2, src, dst, h2, nE);
        transform_kernel<16, 2, true><<<nodeBlocks, B, 0, stream>>>(h2, Wrel3, Wroot3, b3, t3, h3, N);
        scatter_kernel<2><<<((size_t)nE * 2 + B - 1) / B, B, 0, stream>>>(t3, src, dst, h3, nE);
        softmax2_kernel<<<nodeBlocks, B, 0, stream>>>(h3, (float*)d_out, N);
    }
}

// Round 5
// 407.867 us; speedup vs baseline: 2.7921x; 2.7921x over previous
//
#include <hip/hip_runtime.h>
#include <hip/hip_bf16.h>

// 3-layer GraphConv (PyG) + softmax, 100k nodes, 1.6M edges, all f32.
// R2: f32 global atomics ~306G/s scattered -> pull-gather wins.
// R3: per-node CSR bucket scatter = 128us (write amplification 16x).
// R4: coarse cursors = same-address atomic serialization (2050/addr, 376us);
//     coarse-block aggregation starved gather MLP. Both reverted.
// R5: two-phase placement: chunked LDS-hist + batched reservations (<=196
//     atomics/addr) -> records grouped by 128-node bucket; then per-bucket
//     block places via 128 LDS cursors into dense rowptr windows.
//     Gather stays fine-grained (per-(node,f) thread), unroll 8.

#define RNODES 128
#define NB_MAX 1024
#define CH 8192            // edges per bucketize chunk

// ---------------- transform: t = act(x)@Wrel ; acc = act(x)@Wroot + b -------
template <int Fin, int Fout, bool RELU>
__global__ void transform_kernel(const float* __restrict__ x,
                                 const float* __restrict__ Wrel,
                                 const float* __restrict__ Wroot,
                                 const float* __restrict__ bias,
                                 float* __restrict__ t,
                                 float* __restrict__ acc,
                                 int N) {
    __shared__ float sRel[Fin * Fout];
    __shared__ float sRoot[Fin * Fout];
    __shared__ float sB[Fout];
    for (int i = threadIdx.x; i < Fin * Fout; i += blockDim.x) {
        sRel[i]  = Wrel[i];
        sRoot[i] = Wroot[i];
    }
    if (threadIdx.x < Fout) sB[threadIdx.x] = bias[threadIdx.x];
    __syncthreads();

    int n = blockIdx.x * blockDim.x + threadIdx.x;
    if (n >= N) return;

    float xi[Fin];
#pragma unroll
    for (int k = 0; k < Fin; ++k) {
        float v = x[(long)n * Fin + k];
        if (RELU) v = fmaxf(v, 0.0f);
        xi[k] = v;
    }

    for (int f = 0; f < Fout; ++f) {
        float a = 0.0f, r = 0.0f;
#pragma unroll
        for (int k = 0; k < Fin; ++k) {
            a = fmaf(xi[k], sRel[k * Fout + f], a);
            r = fmaf(xi[k], sRoot[k * Fout + f], r);
        }
        t[(long)n * Fout + f]   = a;
        acc[(long)n * Fout + f] = r + sB[f];
    }
}

// ---------------- CSR rowptr build (R3-proven) -----------------------------
__global__ void hist_node_kernel(const int* __restrict__ dst, int* __restrict__ counts, int nE) {
    int e = blockIdx.x * blockDim.x + threadIdx.x;
    if (e < nE) atomicAdd(&counts[dst[e]], 1);
}

__global__ void block_sum_kernel(const int* __restrict__ counts, int* __restrict__ partials, int N) {
    __shared__ int s[256];
    int i = blockIdx.x * 256 + threadIdx.x;
    s[threadIdx.x] = (i < N) ? counts[i] : 0;
    __syncthreads();
    for (int off = 128; off > 0; off >>= 1) {
        if (threadIdx.x < off) s[threadIdx.x] += s[threadIdx.x + off];
        __syncthreads();
    }
    if (threadIdx.x == 0) partials[blockIdx.x] = s[0];
}

__global__ void scan_top_kernel(int* __restrict__ partials, int nb) {
    __shared__ int s[512];
    int t = threadIdx.x;
    s[t] = (t < nb) ? partials[t] : 0;
    __syncthreads();
    for (int off = 1; off < 512; off <<= 1) {
        int v = (t >= off) ? s[t - off] : 0;
        __syncthreads();
        s[t] += v;
        __syncthreads();
    }
    if (t < nb) partials[t] = (t == 0) ? 0 : s[t - 1];
}

__global__ void scan_final_kernel(const int* __restrict__ counts,
                                  const int* __restrict__ partials,
                                  int* __restrict__ rowptr, int N, int nE) {
    __shared__ int s[256];
    int t = threadIdx.x;
    int i = blockIdx.x * 256 + t;
    int v = (i < N) ? counts[i] : 0;
    s[t] = v;
    __syncthreads();
    for (int off = 1; off < 256; off <<= 1) {
        int u = (t >= off) ? s[t - off] : 0;
        __syncthreads();
        s[t] += u;
        __syncthreads();
    }
    if (i < N) rowptr[i] = partials[blockIdx.x] + s[t] - v;
    if (i == 0) rowptr[N] = nE;
}

__global__ void init_gcursor_kernel(const int* __restrict__ rowptr,
                                    int* __restrict__ gcursor, int NB) {
    int b = blockIdx.x * blockDim.x + threadIdx.x;
    if (b < NB) gcursor[b] = rowptr[b * RNODES];
}

// ---------------- phase A: chunked coarse bucketize ------------------------
// One block per CH-edge chunk. LDS hist over buckets, ONE batched global
// reservation per (chunk,bucket) (~196 atomics/addr max), dense appends.
__global__ void bucketize_chunked_kernel(const int* __restrict__ src,
                                         const int* __restrict__ dst,
                                         int* __restrict__ gcursor,
                                         unsigned int* __restrict__ records,
                                         int nE, int NB) {
    __shared__ int chist[NB_MAX];
    __shared__ int sbase[NB_MAX];
    const int e0 = blockIdx.x * CH;
    const int e1 = min(e0 + CH, nE);

    for (int b = threadIdx.x; b < NB; b += blockDim.x) chist[b] = 0;
    __syncthreads();
    for (int e = e0 + threadIdx.x; e < e1; e += blockDim.x)
        atomicAdd(&chist[dst[e] >> 7], 1);
    __syncthreads();
    for (int b = threadIdx.x; b < NB; b += blockDim.x) {
        int c = chist[b];
        sbase[b] = c ? atomicAdd(&gcursor[b], c) : 0;
        chist[b] = 0;   // reuse as local cursor
    }
    __syncthreads();
    for (int e = e0 + threadIdx.x; e < e1; e += blockDim.x) {
        int d = dst[e];
        int b = d >> 7;
        int l = atomicAdd(&chist[b], 1);
        records[sbase[b] + l] = (unsigned int)src[e] | ((unsigned int)(d & 127) << 17);
    }
}

// ---------------- phase B: fine placement via LDS cursors ------------------
__global__ void place_fine_kernel(const unsigned int* __restrict__ records,
                                  const int* __restrict__ rowptr,
                                  int* __restrict__ srcs_sorted, int N) {
    __shared__ int lcur[RNODES];
    const int b    = blockIdx.x;
    const int base = b * RNODES;
    const int nn   = min(RNODES, N - base);
    if (threadIdx.x < nn) lcur[threadIdx.x] = rowptr[base + threadIdx.x];
    __syncthreads();
    const int beg = rowptr[base];
    const int end = rowptr[base + nn];
    for (int i = beg + threadIdx.x; i < end; i += blockDim.x) {
        unsigned int rec = records[i];
        int pos = atomicAdd(&lcur[rec >> 17], 1);
        srcs_sorted[pos] = (int)(rec & 0x1FFFFu);
    }
}

// ---------------- pull aggregation (R3-proven, unroll 8) -------------------
template <int F, int U, bool SOFTMAX>
__global__ void gather_agg_kernel(const float* __restrict__ t,
                                  const int* __restrict__ rowptr,
                                  const int* __restrict__ srcs,
                                  const float* __restrict__ rootacc,
                                  float* __restrict__ out, int N) {
    int tid = blockIdx.x * blockDim.x + threadIdx.x;
    int n = tid / F;
    if (n >= N) return;
    int f = tid & (F - 1);
    const float* tf = t + f;
    int beg = rowptr[n], end = rowptr[n + 1];
    float sum = 0.0f;
    int e = beg;
    for (; e + U <= end; e += U) {
        int s[U];
        float v[U];
#pragma unroll
        for (int u = 0; u < U; ++u) s[u] = srcs[e + u];
#pragma unroll
        for (int u = 0; u < U; ++u) v[u] = tf[(long)s[u] * F];
#pragma unroll
        for (int u = 0; u < U; ++u) sum += v[u];
    }
    for (; e < end; ++e) sum += tf[(long)srcs[e] * F];

    float v = rootacc[(long)n * F + f] + sum;
    if (!SOFTMAX) {
        out[(long)n * F + f] = v;
    } else {
        float o = __shfl_xor(v, 1, 64);
        float m = fmaxf(v, o);
        float ev = __expf(v - m), eo = __expf(o - m);
        out[(long)n * F + f] = ev / (ev + eo);
    }
}

// ---------------- fallback (R2 atomic path) --------------------------------
template <int F>
__global__ void scatter_kernel(const float* __restrict__ t,
                               const int* __restrict__ src,
                               const int* __restrict__ dst,
                               float* __restrict__ acc, int nE) {
    int tid = blockIdx.x * blockDim.x + threadIdx.x;
    int e = tid / F;
    if (e >= nE) return;
    int f = tid & (F - 1);
    atomicAdd(acc + (long)dst[e] * F + f, t[(long)src[e] * F + f]);
}

__global__ void softmax2_kernel(const float* __restrict__ h, float* __restrict__ out, int N) {
    int n = blockIdx.x * blockDim.x + threadIdx.x;
    if (n >= N) return;
    float a = h[2 * n], b = h[2 * n + 1];
    float m = fmaxf(a, b);
    float ea = __expf(a - m), eb = __expf(b - m);
    float inv = 1.0f / (ea + eb);
    out[2 * n] = ea * inv;
    out[2 * n + 1] = eb * inv;
}

extern "C" void kernel_launch(void* const* d_in, const int* in_sizes, int n_in,
                              void* d_out, int out_size, void* d_ws, size_t ws_size,
                              hipStream_t stream) {
    const float* z      = (const float*)d_in[0];
    const int*   ei     = (const int*)d_in[1];
    const float* Wrel1  = (const float*)d_in[2];
    const float* Wroot1 = (const float*)d_in[3];
    const float* b1     = (const float*)d_in[4];
    const float* Wrel2  = (const float*)d_in[5];
    const float* Wroot2 = (const float*)d_in[6];
    const float* b2     = (const float*)d_in[7];
    const float* Wrel3  = (const float*)d_in[8];
    const float* Wroot3 = (const float*)d_in[9];
    const float* b3     = (const float*)d_in[10];

    const int N  = in_sizes[0] / 64;   // 100000
    const int nE = in_sizes[1] / 2;    // 1600000
    const int* src = ei;
    const int* dst = ei + nE;
    const int NB = (N + RNODES - 1) / RNODES;   // 782

    // Float regions (ping-pong, 12.8 MB each):
    //   regionA: [records (build phase)] -> t1[N*32] -> { t2[N*16] | h2[N*16] }
    //   regionB: h1[N*32] -> t3[N*2]
    float* regionA = (float*)d_ws;
    float* regionB = regionA + (size_t)N * 32;
    float* t1 = regionA;
    float* h1 = regionB;
    float* t2 = regionA;
    float* h2 = regionA + (size_t)N * 16;
    float* t3 = regionB;
    float* h3 = regionB + (size_t)N * 2;
    unsigned int* records = (unsigned int*)regionA;   // transient, pre-t1

    // Int region: ncount[N], rowptr[N+1], partials[512], gcursor[NB_MAX], srcs_sorted[nE]
    int* ibase       = (int*)(regionB + (size_t)N * 32);
    int* ncount      = ibase;
    int* rowptr      = ncount + N;
    int* partials    = rowptr + N + 1;
    int* gcursor     = partials + 512;
    int* srcs_sorted = gcursor + NB_MAX;

    size_t needed = (size_t)N * 64 * sizeof(float)
                  + ((size_t)N + (size_t)N + 1 + 512 + NB_MAX + (size_t)nE) * sizeof(int);

    const int B = 256;
    const int nodeBlocks  = (N + B - 1) / B;
    const int edgeBlocks  = (nE + B - 1) / B;
    const int chunkBlocks = (nE + CH - 1) / CH;
    const bool packOK = (N <= (1 << 17)) && (NB <= NB_MAX) && ((size_t)nE * 4 <= (size_t)N * 32 * 4);

    if (ws_size >= needed && packOK) {
        // ---- build: rowptr ----
        hipMemsetAsync(ncount, 0, (size_t)N * sizeof(int), stream);
        hist_node_kernel<<<edgeBlocks, B, 0, stream>>>(dst, ncount, nE);
        block_sum_kernel<<<nodeBlocks, B, 0, stream>>>(ncount, partials, N);
        scan_top_kernel<<<1, 512, 0, stream>>>(partials, nodeBlocks);
        scan_final_kernel<<<nodeBlocks, B, 0, stream>>>(ncount, partials, rowptr, N, nE);
        // ---- build: two-phase placement ----
        init_gcursor_kernel<<<(NB + B - 1) / B, B, 0, stream>>>(rowptr, gcursor, NB);
        bucketize_chunked_kernel<<<chunkBlocks, B, 0, stream>>>(src, dst, gcursor, records, nE, NB);
        place_fine_kernel<<<NB, B, 0, stream>>>(records, rowptr, srcs_sorted, N);

        // ---- Layer 1: 64 -> 32 ----
        transform_kernel<64, 32, false><<<nodeBlocks, B, 0, stream>>>(z, Wrel1, Wroot1, b1, t1, h1, N);
        gather_agg_kernel<32, 8, false><<<((size_t)N * 32 + B - 1) / B, B, 0, stream>>>(
            t1, rowptr, srcs_sorted, h1, h1, N);

        // ---- Layer 2: 32 -> 16 ----
        transform_kernel<32, 16, true><<<nodeBlocks, B, 0, stream>>>(h1, Wrel2, Wroot2, b2, t2, h2, N);
        gather_agg_kernel<16, 8, false><<<((size_t)N * 16 + B - 1) / B, B, 0, stream>>>(
            t2, rowptr, srcs_sorted, h2, h2, N);

        // ---- Layer 3: 16 -> 2, softmax fused ----
        transform_kernel<16, 2, true><<<nodeBlocks, B, 0, stream>>>(h2, Wrel3, Wroot3, b3, t3, h3, N);
        gather_agg_kernel<2, 4, true><<<((size_t)N * 2 + B - 1) / B, B, 0, stream>>>(
            t3, rowptr, srcs_sorted, h3, (float*)d_out, N);
    } else {
        // ---- fallback: R2 atomic-scatter path ----
        transform_kernel<64, 32, false><<<nodeBlocks, B, 0, stream>>>(z, Wrel1, Wroot1, b1, t1, h1, N);
        scatter_kernel<32><<<((size_t)nE * 32 + B - 1) / B, B, 0, stream>>>(t1, src, dst, h1, nE);
        transform_kernel<32, 16, true><<<nodeBlocks, B, 0, stream>>>(h1, Wrel2, Wroot2, b2, t2, h2, N);
        scatter_kernel<16><<<((size_t)nE * 16 + B - 1) / B, B, 0, stream>>>(t2, src, dst, h2, nE);
        transform_kernel<16, 2, true><<<nodeBlocks, B, 0, stream>>>(h2, Wrel3, Wroot3, b3, t3, h3, N);
        scatter_kernel<2><<<((size_t)nE * 2 + B - 1) / B, B, 0, stream>>>(t3, src, dst, h3, nE);
        softmax2_kernel<<<nodeBlocks, B, 0, stream>>>(h3, (float*)d_out, N);
    }
}